// Round 4
// baseline (56.412 us; speedup 1.0000x reference)
//
#include <hip/hip_runtime.h>

// ---------------------------------------------------------------------------
// One THREAD per 3x3 patch (32768 patches). No statevector.
// Ring tensor network (bond dim <= 4), Hermitian-compressed messages:
//  * RX embedding + layer-0 Rot -> product state v_q = Rot0_q RX(a_q)|0>.
//  * Layer-0 CNOT ring = GF(2) basis permutation -> amp[x] = prod v_q[s_q(x)].
//  * Layer-1 CNOTs commute through Z0 -> observable Z0 Z1 Z3 Z5 Z7; layer-1
//    Rots on {2,4,6,8} drop; {0,1,3,5,7} conjugate Z -> M_q.
//  * c_q(a,b) = conj(v_q[a]) v_q[b] is affine in (cos a_q, sin a_q):
//    c = K0 + Kc*cos(a) + Ks*sin(a)  (double-angle identities).
// R4: concentrate waves — 64 blocks x 512 threads (8 waves/block, 2/SIMD on
// 64 CUs) instead of 512x64 over all 256 CUs. The kernel was cold-start
// bound (per-CU icache/L1 misses with ~2 waves/CU and nothing to hide them);
// fewer CUs + more waves/CU amortizes the cold fetch and dispatch packets.
// ---------------------------------------------------------------------------

struct H4 { float p00, p11, pr, pi; };

// R(g,g') = sum_{a,b} P[a,b] * c(a^g, b^g')   (Hermitian in/out)
__device__ __forceinline__ H4 hsc(H4 P, float4 c) {
    H4 R;
    float t1 = P.pr * c.z - P.pi * c.w;
    float t2 = P.pr * c.z + P.pi * c.w;
    R.p00 = P.p00 * c.x + P.p11 * c.y + 2.f * t1;
    R.p11 = P.p00 * c.y + P.p11 * c.x + 2.f * t2;
    R.pr  = (P.p00 + P.p11) * c.z + P.pr * (c.x + c.y);
    R.pi  = (P.p00 - P.p11) * c.w + P.pi * (c.x - c.y);
    return R;
}

// elementwise multiply by M = [[m.x, m.y+i*m.z], [m.y-i*m.z, -m.x]]
__device__ __forceinline__ H4 mhad(H4 P, float4 m) {
    H4 R;
    R.p00 =  P.p00 * m.x;
    R.p11 = -P.p11 * m.x;
    R.pr  = P.pr * m.y - P.pi * m.z;
    R.pi  = P.pr * m.z + P.pi * m.y;
    return R;
}

// inner(x,x') = sum_g m_g * c(g^x, g^x')
__device__ __forceinline__ H4 expand2(float m0, float m1, float4 c) {
    H4 R;
    R.p00 = m0 * c.x + m1 * c.y;
    R.p11 = m0 * c.y + m1 * c.x;
    R.pr  = (m0 + m1) * c.z;
    R.pi  = (m0 - m1) * c.w;
    return R;
}

__global__ __launch_bounds__(512, 2) void qsim(const float* __restrict__ x,
                                               const float* __restrict__ wts,
                                               float* __restrict__ out) {
    __shared__ float4 k0s[9], kcs[9], kss[9];  // affine c-table constants
    __shared__ float4 mqs[5];                  // M for Q={0,1,3,5,7}

    const int t = threadIdx.x;
    const int p = blockIdx.x * 512 + t;          // patch id 0..32767
    const int b = p >> 12, h = (p >> 6) & 63, w = p & 63;

    // prefetch 9 pixels: clamped address, always load, select 0 at border
    float av[9];
#pragma unroll
    for (int q = 0; q < 9; ++q) {
        const int i = h + q / 3 - 1, j = w + q % 3 - 1;
        const int ic = min(max(i, 0), 63), jc = min(max(j, 0), 63);
        float a = x[(b << 12) + (ic << 6) + jc];
        av[q] = ((unsigned)i < 64u && (unsigned)j < 64u) ? a : 0.f;
    }

    if (t < 9) {
        // layer-0 Rot matrix for qubit t
        float phi = wts[t * 3 + 0], th = wts[t * 3 + 1], om = wts[t * 3 + 2];
        float st, ct; __sincosf(0.5f * th, &st, &ct);
        float sp, cp; __sincosf(0.5f * (phi + om), &sp, &cp);
        float sm, cm; __sincosf(0.5f * (phi - om), &sm, &cm);
        float u00r =  ct * cp, u00i = -ct * sp;
        float u01r = -st * cm, u01i = -st * sm;
        float u10r =  st * cm, u10i = -st * sm;
        float u11r =  ct * cp, u11i =  ct * sp;
        float A00 = u00r * u00r + u00i * u00i, B00 = u01r * u01r + u01i * u01i;
        float C00 = 2.f * (u00r * u01i - u00i * u01r);
        float A11 = u10r * u10r + u10i * u10i, B11 = u11r * u11r + u11i * u11i;
        float C11 = 2.f * (u10r * u11i - u10i * u11r);
        float Pr = u00r * u10r + u00i * u10i, Qr = u01r * u11r + u01i * u11i;
        float Rr = u00r * u11i + u01i * u10r - u00i * u11r - u01r * u10i;
        float Pi = u00r * u10i - u00i * u10r, Qi = u01r * u11i - u01i * u11r;
        float Ri = -u00r * u11r + u01i * u10i - u00i * u11i + u01r * u10r;
        k0s[t] = make_float4(0.5f * (A00 + B00), 0.5f * (A11 + B11),
                             0.5f * (Pr + Qr),   0.5f * (Pi + Qi));
        kcs[t] = make_float4(0.5f * (A00 - B00), 0.5f * (A11 - B11),
                             0.5f * (Pr - Qr),   0.5f * (Pi - Qi));
        kss[t] = make_float4(0.5f * C00, 0.5f * C11, 0.5f * Rr, 0.5f * Ri);
    } else if (t < 14) {
        const int k = t - 9;
        const int q = (k == 0) ? 0 : 2 * k - 1;   // {0,1,3,5,7}
        float phi = wts[27 + q * 3 + 0], th = wts[27 + q * 3 + 1];
        float sth, cth; __sincosf(th, &sth, &cth);
        float sph, cph; __sincosf(phi, &sph, &cph);
        mqs[k] = make_float4(cth, -sth * cph, -sth * sph, 0.f);
    }
    __syncthreads();

    // per-qubit Hermitian factors via affine form
    float4 cq[9];
#pragma unroll
    for (int q = 0; q < 9; ++q) {
        float sa, ca; __sincosf(av[q], &sa, &ca);
        float4 K0 = k0s[q], Kc = kcs[q], Ks = kss[q];
        cq[q].x = K0.x + Kc.x * ca + Ks.x * sa;
        cq[q].y = K0.y + Kc.y * ca + Ks.y * sa;
        cq[q].z = K0.z + Kc.z * ca + Ks.z * sa;
        cq[q].w = K0.w + Kc.w * ca + Ks.w * sa;
    }

    float4 m0 = mqs[0], m1 = mqs[1], m2 = mqs[2], m3 = mqs[3], m4 = mqs[4];

    float E = 0.f;
#pragma unroll
    for (int beta = 0; beta < 2; ++beta) {
        // site 0
        H4 P;
        if (beta == 0) P = H4{cq[0].x, cq[0].y, cq[0].z, cq[0].w};
        else           P = H4{cq[0].y, cq[0].x, cq[0].z, -cq[0].w};
        P = mhad(P, m0);
        // site 1
        H4 R = hsc(P, cq[1]);
        if (beta == 1) { float tmp = R.p00; R.p00 = R.p11; R.p11 = tmp; R.pi = -R.pi; }
        P = mhad(R, m1);
        // site 2 (delta)
        R = hsc(P, cq[2]);
        // site 3
        P = mhad(expand2(R.p00, R.p11, cq[3]), m2);
        // site 4 (delta)
        R = hsc(P, cq[4]);
        // site 5
        P = mhad(expand2(R.p00, R.p11, cq[5]), m3);
        // site 6 (delta)
        R = hsc(P, cq[6]);
        // site 7
        P = mhad(expand2(R.p00, R.p11, cq[7]), m4);
        // close with site 8
        R = hsc(P, cq[8]);
        E += (beta == 0) ? R.p00 : R.p11;
    }

    out[p] = E;
}

extern "C" void kernel_launch(void* const* d_in, const int* in_sizes, int n_in,
                              void* d_out, int out_size, void* d_ws, size_t ws_size,
                              hipStream_t stream) {
    const float* x   = (const float*)d_in[0];   // (8,1,64,64) fp32
    const float* wts = (const float*)d_in[1];   // (2,9,3) fp32
    float* out = (float*)d_out;                 // (8,1,64,64) fp32
    qsim<<<64, 512, 0, stream>>>(x, wts, out);
}